// Round 1
// baseline (866.581 us; speedup 1.0000x reference)
//
#include <hip/hip_runtime.h>
#include <cstdint>
#include <cstddef>

// Better_Transformer: B=16384, IN=4096, P=8, D=512
// out = swish2( blockmm( swish1( blockmm(x*g1+nb1, W1)+b1 )*g3+nb3, W2)+b2 ) + x
// Strategy: bf16 MFMA (16x16x32), m97-style 128x128 tiles, BK=64.
//  k0: transpose+convert W1,W2 -> bf16 [p][n][k] in ws
//  k1: GEMM1 (A from fp32 x, inline cvt) -> o1 bf16 in ws (activation fused, *g3+nb3 pre-applied)
//  k2: GEMM2 (A,B via global_load_lds) -> fp32 out with residual from fp32 x

#define B_ROWS 16384
#define IN_SZ  4096
#define P_PART 8
#define D_DIM  512

typedef unsigned short ushort_t;
typedef __attribute__((ext_vector_type(8))) short short8;   // 8 x bf16 bits (4 VGPRs)
typedef __attribute__((ext_vector_type(4))) float f32x4;    // MFMA accumulator

__device__ inline unsigned short f2bf(float f) {
  union { float f; unsigned int u; } c; c.f = f;
  unsigned int u = c.u;
  return (unsigned short)((u + 0x7fffu + ((u >> 16) & 1u)) >> 16);  // RNE
}

__device__ inline void gld_to_lds16(const void* g, void* l) {
  // 16B per lane, LDS dest = wave-uniform base + lane*16
  __builtin_amdgcn_global_load_lds((const __attribute__((address_space(1))) void*)g,
                                   (__attribute__((address_space(3))) void*)l,
                                   16, 0, 0);
}

// ---------------------------------------------------------------- weight prep
// Wt[p][n][k] = W[p][k][n], fp32 -> bf16. grid (8 ktile, 8 ntile, 16), block 256
__global__ __launch_bounds__(256) void wconv_kernel(const float* __restrict__ w1,
                                                    const float* __restrict__ w2,
                                                    ushort_t* __restrict__ wt1,
                                                    ushort_t* __restrict__ wt2) {
  __shared__ float tile[64][68];  // +4 pad
  const int p = blockIdx.z & 7;
  const float*  src = (blockIdx.z < 8) ? w1 : w2;
  ushort_t*     dst = (blockIdx.z < 8) ? wt1 : wt2;
  const int k0 = blockIdx.x * 64;
  const int n0 = blockIdx.y * 64;
  const int t = threadIdx.x;

  const float* base = src + ((size_t)p * D_DIM + k0) * D_DIM + n0;
#pragma unroll
  for (int i = 0; i < 4; ++i) {
    int f = t + i * 256;          // 0..1023
    int kr = f >> 4;
    int c4 = f & 15;
    float4 v = *(const float4*)(base + (size_t)kr * D_DIM + c4 * 4);
    *(float4*)(&tile[kr][c4 * 4]) = v;   // row stride 68 floats (272B, 16B-mult)
  }
  __syncthreads();
  ushort_t* obase = dst + ((size_t)p * D_DIM + n0) * D_DIM + k0;
#pragma unroll
  for (int i = 0; i < 4; ++i) {
    int f = t + i * 256;
    int nr = f >> 4;
    int kc = (f & 15) * 4;
    unsigned int lo = f2bf(tile[kc + 0][nr]) | ((unsigned int)f2bf(tile[kc + 1][nr]) << 16);
    unsigned int hi = f2bf(tile[kc + 2][nr]) | ((unsigned int)f2bf(tile[kc + 3][nr]) << 16);
    uint2 pk; pk.x = lo; pk.y = hi;
    *(uint2*)(obase + (size_t)nr * D_DIM + kc) = pk;
  }
}

// ---------------------------------------------------------------- GEMM1
// C = act( (x*g1+nb1)[128,512] @ W1_p ) ; store o1 = act*g3+nb3 as bf16
// grid (128 mtile, 4 ntile, 8 p), block 256 (4 waves, 2x2, 64x64 per wave)
__global__ __launch_bounds__(256) void gemm1_kernel(
    const float* __restrict__ x, const ushort_t* __restrict__ wt1,
    const float* __restrict__ bias1, const float* __restrict__ gamma1,
    const float* __restrict__ beta1,
    const float* __restrict__ gain1, const float* __restrict__ nbias1,
    const float* __restrict__ gain3, const float* __restrict__ nbias3,
    ushort_t* __restrict__ o1) {
  __shared__ __align__(16) ushort_t As[128 * 64];  // [m][k]
  __shared__ __align__(16) ushort_t Bs[128 * 64];  // [n][k]

  const int t = threadIdx.x;
  const int lane = t & 63, wid = t >> 6;
  const int wm = wid & 1, wn = wid >> 1;
  const int l15 = lane & 15, quad = lane >> 4;
  const int m0 = blockIdx.x * 128;
  const int n0 = blockIdx.y * 128;
  const int p  = blockIdx.z;

  const float g1 = gain1[0], nb1 = nbias1[0];
  const float g3 = gain3[0], nb3 = nbias3[0];

  f32x4 acc[4][4];
#pragma unroll
  for (int i = 0; i < 4; ++i)
#pragma unroll
    for (int j = 0; j < 4; ++j) acc[i][j] = (f32x4)(0.0f);

  const ushort_t* wbase = wt1 + (size_t)p * D_DIM * D_DIM;

  for (int kt = 0; kt < 8; ++kt) {
    __syncthreads();
    // --- stage A: 128x64 fp32 -> bf16 (prescale fused)
    const float* xtile = x + (size_t)m0 * IN_SZ + p * D_DIM + kt * 64;
#pragma unroll
    for (int i = 0; i < 8; ++i) {
      int f = t + i * 256;               // 0..2047
      int row = f >> 4, c4 = f & 15;
      float4 v = *(const float4*)(xtile + (size_t)row * IN_SZ + c4 * 4);
      v.x = v.x * g1 + nb1; v.y = v.y * g1 + nb1;
      v.z = v.z * g1 + nb1; v.w = v.w * g1 + nb1;
      uint2 pk;
      pk.x = f2bf(v.x) | ((unsigned int)f2bf(v.y) << 16);
      pk.y = f2bf(v.z) | ((unsigned int)f2bf(v.w) << 16);
      *(uint2*)(&As[f * 4]) = pk;        // byte offset f*8 == (row*64+c4*4)*2
    }
    // --- stage B: Wt1[p][n0+n][kt*64 + k] via global_load_lds, 4 calls/wave
#pragma unroll
    for (int c = 0; c < 4; ++c) {
      int off = (wid * 4 + c) * 1024;    // byte offset into Bs (wave-uniform)
      int lb = off + lane * 16;
      int n = lb >> 7, kb = lb & 127;
      const ushort_t* g = wbase + (size_t)(n0 + n) * D_DIM + kt * 64 + (kb >> 1);
      gld_to_lds16(g, (char*)Bs + off);
    }
    __syncthreads();
    // --- compute
#pragma unroll
    for (int kk = 0; kk < 2; ++kk) {
      const int kof = kk * 32 + quad * 8;
      short8 a[4], b[4];
#pragma unroll
      for (int i = 0; i < 4; ++i)
        a[i] = *(const short8*)(&As[(wm * 64 + i * 16 + l15) * 64 + kof]);
#pragma unroll
      for (int j = 0; j < 4; ++j)
        b[j] = *(const short8*)(&Bs[(wn * 64 + j * 16 + l15) * 64 + kof]);
#pragma unroll
      for (int i = 0; i < 4; ++i)
#pragma unroll
        for (int j = 0; j < 4; ++j)
          acc[i][j] = __builtin_amdgcn_mfma_f32_16x16x32_bf16(a[i], b[j], acc[i][j], 0, 0, 0);
    }
  }

  // --- epilogue: bias1 + swish(gamma1,beta1), then *g3+nb3, store bf16
  const int colg0 = p * D_DIM + n0 + wn * 64;
  const int row0 = m0 + wm * 64 + quad * 4;
#pragma unroll
  for (int j = 0; j < 4; ++j) {
    int col = colg0 + j * 16 + l15;
    float bv = bias1[col], ga = gamma1[col], be = beta1[col];
#pragma unroll
    for (int i = 0; i < 4; ++i) {
      int r0 = row0 + i * 16;
#pragma unroll
      for (int r = 0; r < 4; ++r) {
        float v = acc[i][j][r] + bv;
        float sg = 1.0f / (1.0f + __expf(-be * v));
        float o = (ga + sg * (1.0f - ga)) * v;
        o = o * g3 + nb3;
        o1[(size_t)(r0 + r) * IN_SZ + col] = f2bf(o);
      }
    }
  }
}

// ---------------------------------------------------------------- GEMM2
// out = act( o1s[128,512] @ W2_p + b2 ) + x   (fp32 residual, fp32 out)
__global__ __launch_bounds__(256) void gemm2_kernel(
    const ushort_t* __restrict__ o1, const ushort_t* __restrict__ wt2,
    const float* __restrict__ bias2, const float* __restrict__ gamma3,
    const float* __restrict__ beta3,
    const float* __restrict__ x, float* __restrict__ out) {
  __shared__ __align__(16) ushort_t As[128 * 64];
  __shared__ __align__(16) ushort_t Bs[128 * 64];

  const int t = threadIdx.x;
  const int lane = t & 63, wid = t >> 6;
  const int wm = wid & 1, wn = wid >> 1;
  const int l15 = lane & 15, quad = lane >> 4;
  const int m0 = blockIdx.x * 128;
  const int n0 = blockIdx.y * 128;
  const int p  = blockIdx.z;

  f32x4 acc[4][4];
#pragma unroll
  for (int i = 0; i < 4; ++i)
#pragma unroll
    for (int j = 0; j < 4; ++j) acc[i][j] = (f32x4)(0.0f);

  const ushort_t* wbase = wt2 + (size_t)p * D_DIM * D_DIM;

  for (int kt = 0; kt < 8; ++kt) {
    __syncthreads();
#pragma unroll
    for (int c = 0; c < 4; ++c) {
      int off = (wid * 4 + c) * 1024;
      int lb = off + lane * 16;
      int m = lb >> 7, kb = lb & 127;
      const ushort_t* g = o1 + (size_t)(m0 + m) * IN_SZ + p * D_DIM + kt * 64 + (kb >> 1);
      gld_to_lds16(g, (char*)As + off);
    }
#pragma unroll
    for (int c = 0; c < 4; ++c) {
      int off = (wid * 4 + c) * 1024;
      int lb = off + lane * 16;
      int n = lb >> 7, kb = lb & 127;
      const ushort_t* g = wbase + (size_t)(n0 + n) * D_DIM + kt * 64 + (kb >> 1);
      gld_to_lds16(g, (char*)Bs + off);
    }
    __syncthreads();
#pragma unroll
    for (int kk = 0; kk < 2; ++kk) {
      const int kof = kk * 32 + quad * 8;
      short8 a[4], b[4];
#pragma unroll
      for (int i = 0; i < 4; ++i)
        a[i] = *(const short8*)(&As[(wm * 64 + i * 16 + l15) * 64 + kof]);
#pragma unroll
      for (int j = 0; j < 4; ++j)
        b[j] = *(const short8*)(&Bs[(wn * 64 + j * 16 + l15) * 64 + kof]);
#pragma unroll
      for (int i = 0; i < 4; ++i)
#pragma unroll
        for (int j = 0; j < 4; ++j)
          acc[i][j] = __builtin_amdgcn_mfma_f32_16x16x32_bf16(a[i], b[j], acc[i][j], 0, 0, 0);
    }
  }

  const int colg0 = p * D_DIM + n0 + wn * 64;
  const int row0 = m0 + wm * 64 + quad * 4;
#pragma unroll
  for (int j = 0; j < 4; ++j) {
    int col = colg0 + j * 16 + l15;
    float bv = bias2[col], ga = gamma3[col], be = beta3[col];
#pragma unroll
    for (int i = 0; i < 4; ++i) {
      int r0 = row0 + i * 16;
#pragma unroll
      for (int r = 0; r < 4; ++r) {
        float v = acc[i][j][r] + bv;
        float sg = 1.0f / (1.0f + __expf(-be * v));
        float o = (ga + sg * (1.0f - ga)) * v;
        size_t idx = (size_t)(r0 + r) * IN_SZ + col;
        out[idx] = o + x[idx];
      }
    }
  }
}

// ---------------------------------------------------------------- launch
extern "C" void kernel_launch(void* const* d_in, const int* in_sizes, int n_in,
                              void* d_out, int out_size, void* d_ws, size_t ws_size,
                              hipStream_t stream) {
  const float* x      = (const float*)d_in[0];
  const float* w1     = (const float*)d_in[1];
  const float* b1     = (const float*)d_in[2];
  const float* w2     = (const float*)d_in[3];
  const float* b2     = (const float*)d_in[4];
  const float* gamma1 = (const float*)d_in[5];
  const float* beta1  = (const float*)d_in[6];
  const float* gamma3 = (const float*)d_in[7];
  const float* beta3  = (const float*)d_in[8];
  const float* gain1  = (const float*)d_in[9];
  const float* nbias1 = (const float*)d_in[10];
  const float* gain3  = (const float*)d_in[11];
  const float* nbias3 = (const float*)d_in[12];
  float* out = (float*)d_out;

  // ws layout: o1 bf16 [16384][4096] (128MB) | Wt1 bf16 (4MB) | Wt2 bf16 (4MB)
  ushort_t* o1  = (ushort_t*)d_ws;
  ushort_t* wt1 = (ushort_t*)((char*)d_ws + (size_t)B_ROWS * IN_SZ * 2);
  ushort_t* wt2 = wt1 + (size_t)P_PART * D_DIM * D_DIM;

  wconv_kernel<<<dim3(8, 8, 16), 256, 0, stream>>>(w1, w2, wt1, wt2);
  gemm1_kernel<<<dim3(128, 4, 8), 256, 0, stream>>>(x, wt1, b1, gamma1, beta1,
                                                    gain1, nbias1, gain3, nbias3, o1);
  gemm2_kernel<<<dim3(128, 4, 8), 256, 0, stream>>>(o1, wt2, b2, gamma3, beta3, x, out);
}